// Round 5
// baseline (425.569 us; speedup 1.0000x reference)
//
#include <hip/hip_runtime.h>
#include <math.h>
#include <stdint.h>

#define BATCH 512
#define DIM 512
#define NCLASS 100000
#define BN 64
#define BK 128
#define NSTEP (DIM / BK)              /* 4 */
#define NT ((NCLASS + BN - 1) / BN)   /* 1563 */
#define S_SCALE 30.0f
#define COSM 0.8775825618903728f
#define SINM 0.4794255386042030f

typedef unsigned short u16;
typedef __attribute__((ext_vector_type(8))) short short8;
typedef __attribute__((ext_vector_type(4))) float floatx4;

// ws layout (bytes):
//   [0, 524288)            xn bf16 [512][512]
//   [524288, 526336)       tlogit float[512]
//   [526336, 528384)       nll    float[512]
//   [528384, +NT*512*4)    partials [NT][512]  (~3.2 MB)

__device__ __forceinline__ u16 f2bf(float f) {
    union { float f; unsigned int u; } v;
    v.f = f;
    unsigned int u = v.u;
    u += 0x7fffu + ((u >> 16) & 1u);   // round-to-nearest-even
    return (u16)(u >> 16);
}

__device__ __forceinline__ void async_cp16(const void* g, void* l) {
    auto gp = reinterpret_cast<const __attribute__((address_space(1))) unsigned int*>(
        reinterpret_cast<uintptr_t>(g));
    auto lp = reinterpret_cast<__attribute__((address_space(3))) unsigned int*>(
        reinterpret_cast<uintptr_t>(l));
    __builtin_amdgcn_global_load_lds(gp, lp, 16, 0, 0);  // 16B/lane, lane-linear LDS dest
}

// ---------------- Kernel 1: normalize x rows -> bf16 ----------------
__global__ void xnorm_kernel(const float* __restrict__ x, u16* __restrict__ xn) {
    const int row = blockIdx.x;
    const int t = threadIdx.x; // 64 threads = 1 wave
    const floatx4* xr = (const floatx4*)(x + (size_t)row * DIM);
    floatx4 a = xr[t];
    floatx4 b = xr[t + 64];
    float ss = a[0]*a[0] + a[1]*a[1] + a[2]*a[2] + a[3]*a[3]
             + b[0]*b[0] + b[1]*b[1] + b[2]*b[2] + b[3]*b[3];
#pragma unroll
    for (int d = 1; d < 64; d <<= 1) ss += __shfl_xor(ss, d);
    const float rn = 1.0f / fmaxf(sqrtf(ss), 1e-12f);
    ushort4 ua, ub;
    ua.x = f2bf(a[0]*rn); ua.y = f2bf(a[1]*rn); ua.z = f2bf(a[2]*rn); ua.w = f2bf(a[3]*rn);
    ub.x = f2bf(b[0]*rn); ub.y = f2bf(b[1]*rn); ub.z = f2bf(b[2]*rn); ub.w = f2bf(b[3]*rn);
    u16* orow = xn + (size_t)row * DIM;
    *(ushort4*)(orow + 4*t)       = ua;
    *(ushort4*)(orow + 256 + 4*t) = ub;
}

// ---------------- Kernel 2: fused GEMM + partial softmax ----------------
// 512 threads (8 waves), BK=128: per K-step, DMA the fp32 w-slice (32 KB) into
// fbuf, cooperative fp32->bf16 cvt into bbuf (+per-class sumsq), 64 MFMA/wave.
// Single fbuf/bbuf: cvt's fbuf reads end before B2 (next DMA issue); MFMA's
// bbuf reads end before the next B1 (cvt overwrite). waves_per_eu(2) -> 256-reg
// budget so nothing spills (R2-R4 killer).
__global__ __launch_bounds__(512) __attribute__((amdgpu_waves_per_eu(2)))
void arcface_main(const float* __restrict__ w,
                  const u16* __restrict__ xn,
                  const int* __restrict__ target,
                  float* __restrict__ partials,
                  float* __restrict__ tlogit) {
    __shared__ float fbuf[BN * BK];   // 32 KB raw fp32 slice (DMA target)
    __shared__ u16   bbuf[BN * BK];   // 16 KB bf16 tile (16B-granule XOR swizzle)
    __shared__ float ssb[BN];         // per-class sum of squares

    const int t = threadIdx.x;
    const int tile = blockIdx.x;
    const int c0 = tile * BN;

    const int wave = t >> 6;
    const int lane = t & 63;
    const int quad = lane >> 4;
    const int nin  = lane & 15;
    const int mbase = wave * 64;

    const int scl  = t >> 3;   // cvt: class row 0..63
    const int ssub = t & 7;    // cvt: 8 threads/row, 16 floats each

    // --- DMA addressing: 4 calls/wave/step, lane-linear class-major LDS ---
    // granule gi = wave*256 + j*64 + lane (0..2047); class = gi>>5, gq = gi&31
    size_t goff[4];
    int ldsoff[4];
#pragma unroll
    for (int j = 0; j < 4; ++j) {
        const int gi = wave * 256 + j * 64 + lane;
        const int cl = gi >> 5, gq = gi & 31;
        int cls = c0 + cl; if (cls > NCLASS - 1) cls = NCLASS - 1;  // tail clamp
        goff[j] = (size_t)cls * (DIM * 4) + (size_t)gq * 16;
        ldsoff[j] = (wave * 4 + j) * 1024;   // + lane*16 implicit in DMA
    }
    const char* wbytes = (const char*)w;

    // prologue: DMA step 0
#pragma unroll
    for (int j = 0; j < 4; ++j)
        async_cp16(wbytes + goff[j], (char*)fbuf + ldsoff[j]);

    if (t < BN) ssb[t] = 0.f;

    floatx4 acc[4][4];
#pragma unroll
    for (int mi = 0; mi < 4; ++mi)
#pragma unroll
        for (int ni = 0; ni < 4; ++ni) {
            acc[mi][ni][0] = 0.f; acc[mi][ni][1] = 0.f;
            acc[mi][ni][2] = 0.f; acc[mi][ni][3] = 0.f;
        }

    for (int ks = 0; ks < NSTEP; ++ks) {
        __syncthreads();   // B1: fbuf DMA complete; all MFMA reads of bbuf done

        // --- cvt: fbuf -> bbuf (each element once) + per-class sumsq ---
        {
            const float* fb = fbuf + scl * BK + ssub * 16;
            const floatx4 f0 = *(const floatx4*)(fb);
            const floatx4 f1 = *(const floatx4*)(fb + 4);
            const floatx4 f2 = *(const floatx4*)(fb + 8);
            const floatx4 f3 = *(const floatx4*)(fb + 12);
            float ss = f0[0]*f0[0] + f0[1]*f0[1] + f0[2]*f0[2] + f0[3]*f0[3]
                     + f1[0]*f1[0] + f1[1]*f1[1] + f1[2]*f1[2] + f1[3]*f1[3]
                     + f2[0]*f2[0] + f2[1]*f2[1] + f2[2]*f2[2] + f2[3]*f2[3]
                     + f3[0]*f3[0] + f3[1]*f3[1] + f3[2]*f3[2] + f3[3]*f3[3];
            ss += __shfl_xor(ss, 1);
            ss += __shfl_xor(ss, 2);
            ss += __shfl_xor(ss, 4);
            short8 w0, w1;
            w0[0] = (short)f2bf(f0[0]); w0[1] = (short)f2bf(f0[1]);
            w0[2] = (short)f2bf(f0[2]); w0[3] = (short)f2bf(f0[3]);
            w0[4] = (short)f2bf(f1[0]); w0[5] = (short)f2bf(f1[1]);
            w0[6] = (short)f2bf(f1[2]); w0[7] = (short)f2bf(f1[3]);
            w1[0] = (short)f2bf(f2[0]); w1[1] = (short)f2bf(f2[1]);
            w1[2] = (short)f2bf(f2[2]); w1[3] = (short)f2bf(f2[3]);
            w1[4] = (short)f2bf(f3[0]); w1[5] = (short)f2bf(f3[1]);
            w1[6] = (short)f2bf(f3[2]); w1[7] = (short)f2bf(f3[3]);
            const int sw = scl & 15;
            const int g0 = (2 * ssub) ^ sw;
            const int g1 = (2 * ssub + 1) ^ sw;
            *(short8*)(&bbuf[scl * BK + g0 * 8]) = w0;
            *(short8*)(&bbuf[scl * BK + g1 * 8]) = w1;
            if (ssub == 0) ssb[scl] += ss;   // single writer per class per step
        }
        __syncthreads();   // B2: bbuf + ssb visible; fbuf free for next DMA

        // issue DMA for step ks+1 (completes under the MFMA phase)
        if (ks + 1 < NSTEP) {
            const size_t so = (size_t)(ks + 1) * (BK * 4);
#pragma unroll
            for (int j = 0; j < 4; ++j)
                async_cp16(wbytes + goff[j] + so, (char*)fbuf + ldsoff[j]);
        }

        // --- MFMA phase: 4 kk x 16 = 64 MFMA per wave ---
#pragma unroll
        for (int kk = 0; kk < 4; ++kk) {
            short8 a[4], b[4];
            const int kg = ks * BK + kk * 32 + quad * 8;
#pragma unroll
            for (int mi = 0; mi < 4; ++mi)
                a[mi] = *(const short8*)(xn + (size_t)(mbase + mi * 16 + nin) * DIM + kg);
#pragma unroll
            for (int ni = 0; ni < 4; ++ni) {
                const int cl = ni * 16 + nin;
                const int g = (kk * 4 + quad) ^ (cl & 15);
                b[ni] = *(const short8*)(&bbuf[cl * BK + g * 8]);
            }
#pragma unroll
            for (int mi = 0; mi < 4; ++mi)
#pragma unroll
                for (int ni = 0; ni < 4; ++ni)
                    acc[mi][ni] = __builtin_amdgcn_mfma_f32_16x16x32_bf16(
                        a[mi], b[ni], acc[mi][ni], 0, 0, 0);
        }
    }
    // ssb final as of B2(last step); epilogue only reads it

    // --- epilogue: normalize, arcface transform, per-row exp-sum ---
    float rns[4];
#pragma unroll
    for (int ni = 0; ni < 4; ++ni)
        rns[ni] = 1.0f / fmaxf(sqrtf(ssb[ni * 16 + nin]), 1e-12f);

#pragma unroll
    for (int mi = 0; mi < 4; ++mi) {
#pragma unroll
        for (int reg = 0; reg < 4; ++reg) {
            const int m = mbase + mi * 16 + quad * 4 + reg;
            const int tg = target[m];
            float psum = 0.f;
#pragma unroll
            for (int ni = 0; ni < 4; ++ni) {
                const int c = c0 + ni * 16 + nin;
                if (c < NCLASS) {
                    const float cosv = acc[mi][ni][reg] * rns[ni];
                    float lg = S_SCALE * cosv;
                    if (c == tg) {
                        const float sine = sqrtf(fmaxf(1.f - cosv * cosv, 0.f));
                        float phi = cosv * COSM - sine * SINM;
                        if (!(cosv > 0.f)) phi = cosv;   // easy_margin
                        lg = S_SCALE * phi;
                        tlogit[m] = lg;
                    }
                    psum += __expf(lg - S_SCALE);        // fixed shift S (logit <= S)
                }
            }
            psum += __shfl_xor(psum, 1);
            psum += __shfl_xor(psum, 2);
            psum += __shfl_xor(psum, 4);
            psum += __shfl_xor(psum, 8);
            if (nin == 0)
                partials[(size_t)tile * BATCH + m] = psum;   // coalesced per block
        }
    }
}

// ---------------- Kernel 3a: per-row logsumexp + nll ----------------
__global__ void reduce_lse(const float* __restrict__ partials,
                           const float* __restrict__ tlogit,
                           float* __restrict__ nll) {
    const int m = blockIdx.x;
    const int t = threadIdx.x; // 256
    float s = 0.f;
    for (int b = t; b < NT; b += 256) s += partials[(size_t)b * BATCH + m];
#pragma unroll
    for (int d = 1; d < 64; d <<= 1) s += __shfl_xor(s, d);
    __shared__ float red[4];
    if ((t & 63) == 0) red[t >> 6] = s;
    __syncthreads();
    if (t == 0) {
        const float tot = red[0] + red[1] + red[2] + red[3];
        nll[m] = (logf(tot) + S_SCALE) - tlogit[m];
    }
}

// ---------------- Kernel 3b: mean ----------------
__global__ void reduce_mean(const float* __restrict__ nll, float* __restrict__ out) {
    const int t = threadIdx.x; // 512
    float s = nll[t];
#pragma unroll
    for (int d = 1; d < 64; d <<= 1) s += __shfl_xor(s, d);
    __shared__ float red[8];
    if ((t & 63) == 0) red[t >> 6] = s;
    __syncthreads();
    if (t == 0) {
        float tot = 0.f;
#pragma unroll
        for (int i = 0; i < 8; ++i) tot += red[i];
        out[0] = tot / (float)BATCH;
    }
}

extern "C" void kernel_launch(void* const* d_in, const int* in_sizes, int n_in,
                              void* d_out, int out_size, void* d_ws, size_t ws_size,
                              hipStream_t stream) {
    const float* x = (const float*)d_in[0];
    const float* w = (const float*)d_in[1];
    const int* target = (const int*)d_in[2];

    char* ws = (char*)d_ws;
    u16* xn         = (u16*)ws;
    float* tlogit   = (float*)(ws + 524288);
    float* nll      = (float*)(ws + 526336);
    float* partials = (float*)(ws + 528384);

    xnorm_kernel<<<BATCH, 64, 0, stream>>>(x, xn);
    arcface_main<<<NT, 512, 0, stream>>>(w, xn, target, partials, tlogit);
    reduce_lse<<<BATCH, 256, 0, stream>>>(partials, tlogit, nll);
    reduce_mean<<<1, 512, 0, stream>>>(nll, (float*)d_out);
}